// Round 5
// baseline (65.364 us; speedup 1.0000x reference)
//
#include <hip/hip_runtime.h>

#define IW 512
#define IH 512
#define NPIX (IH * IW)
#define NPLANES 24      // B*C
#define NK 6            // steps 1..6 (step 0 is exact identity)
#define GROUPS 4        // plane-split: 6 planes per block
#define PPT (NPLANES / GROUPS)
#define LROW 520        // LDS line stride: 4 guard + 512 data + 4 guard
#define GOFF 4          // data starts at slot 4 (16B-aligned stage writes)

typedef float f4v __attribute__((ext_vector_type(4)));
typedef float f2v __attribute__((ext_vector_type(2)));

struct RowTap { int rowA; float t0, t1; };

// Row taps for one step (depends only on y and inv; branch-free remap
// handles vertical zero-pad: out-of-range row -> weight 0).
__device__ inline RowTap row_prep(float inv, float yf) {
    const float ysv = fmaf(yf, inv, 256.0f);
    const float fy  = floorf(ysv);
    const float wy  = ysv - fy;
    const int y0 = (int)fy;
    const int yb = min(max(y0, 0), IH - 2);
    RowTap rt;
    rt.t0 = (yb == y0 ? 1.0f - wy : 0.0f) + (yb == y0 + 1 ? wy : 0.0f);
    rt.t1 = (yb + 1 == y0 ? 1.0f - wy : 0.0f) + (yb + 1 == y0 + 1 ? wy : 0.0f);
    rt.rowA = yb * IW;
    return rt;
}

__global__ __launch_bounds__(256, 8) void zoomblur_kernel(
    const float* __restrict__ img,
    const float* __restrict__ zoomf,
    float* __restrict__ out)
{
    __shared__ float rrow[NK * LROW];   // 12.5 KB: 6 guarded row-interp lines

    const int tid   = threadIdx.x;
    const int bid   = blockIdx.x;
    const int group = bid & (GROUPS - 1);
    const int y     = bid >> 2;                 // one output row per block
    const int xL    = tid * 2;                  // thread owns pixels xL, xL+1

    const float zf = 0.85f + 0.30f * zoomf[0];
    const float dz = zf - 1.0f;
    const float yf  = (float)y - 256.0f;
    const float xfL = (float)xL - 256.0f;

    // per-step inverse scales (rcp: ~1ulp, well inside tolerance)
    float invs[NK];
#pragma unroll
    for (int s = 1; s <= NK; ++s)
        invs[s - 1] = __builtin_amdgcn_rcpf(fmaf((float)s * (1.0f / 6.0f), dz, 1.0f));

    // ---- per-thread column taps (guard-zero trick: clamp into guards,
    //      keep plain interior weights; guards hold 0 = zero padding) ----
    int   offL[NK], offR[NK];
    float wxL[NK], wxR[NK];
#pragma unroll
    for (int k = 0; k < NK; ++k) {
        const float inv = invs[k];
        const float xsL = fmaf(xfL, inv, 256.0f);
        const float xsR = xsL + inv;
        const float fxL = floorf(xsL);
        const float fxR = floorf(xsR);
        wxL[k] = xsL - fxL;
        wxR[k] = xsR - fxR;
        const int x0L = min(max((int)fxL, -2), IW);   // slots 2..516 (+1)
        const int x0R = min(max((int)fxR, -2), IW);
        offL[k] = k * LROW + GOFF + x0L;
        offR[k] = k * LROW + GOFF + x0R;
    }

    // ---- staging role: thread stages col-quad cq of 3 of the 6 lines ----
    const int sbase = tid >> 7;             // 0 or 1
    const int cq    = (tid & 127) << 2;     // 0..508
    const float invA = sbase ? invs[1] : invs[0];
    const float invB = sbase ? invs[3] : invs[2];
    const float invC = sbase ? invs[5] : invs[4];
    const RowTap r0 = row_prep(invA, yf);
    const RowTap r1 = row_prep(invB, yf);
    const RowTap r2 = row_prep(invC, yf);
    float* w0 = &rrow[(sbase + 0) * LROW + GOFF + cq];
    float* w1 = &rrow[(sbase + 2) * LROW + GOFF + cq];
    float* w2 = &rrow[(sbase + 4) * LROW + GOFF + cq];

    // zero the guard slots once (persist across planes; stage writes only
    // touch slots [GOFF, GOFF+512))
    if (tid < 48) {
        const int line = tid >> 3;
        const int j    = tid & 7;
        const int slot = (j < 4) ? j : 512 + j;   // 0..3, 516..519
        rrow[line * LROW + slot] = 0.0f;
    }

    const int idoff = y * IW + xL;
    const size_t pbase = (size_t)(group * PPT) * NPIX;
    const float* __restrict__ ib = img + pbase;
    float* __restrict__       ob = out + pbase;

#pragma unroll 1
    for (int p = 0; p < PPT; ++p) {
        const float* __restrict__ base = ib + (size_t)p * NPIX;
        // stage: 6 coalesced row loads -> 3 row-interpolated lines
        const f4v a0 = *(const f4v*)(base + r0.rowA + cq);
        const f4v b0 = *(const f4v*)(base + r0.rowA + IW + cq);
        const f4v a1 = *(const f4v*)(base + r1.rowA + cq);
        const f4v b1 = *(const f4v*)(base + r1.rowA + IW + cq);
        const f4v a2 = *(const f4v*)(base + r2.rowA + cq);
        const f4v b2 = *(const f4v*)(base + r2.rowA + IW + cq);
        const f2v idv = *(const f2v*)(base + idoff);   // step 0: identity
        *(f4v*)w0 = r0.t0 * a0 + r0.t1 * b0;
        *(f4v*)w1 = r1.t0 * a1 + r1.t1 * b1;
        *(f4v*)w2 = r2.t0 * a2 + r2.t1 * b2;
        __syncthreads();

        float aL = idv.x, aR = idv.y;
#pragma unroll
        for (int k = 0; k < NK; ++k) {
            const float v0L = rrow[offL[k]];
            const float v1L = rrow[offL[k] + 1];
            const float v0R = rrow[offR[k]];
            const float v1R = rrow[offR[k] + 1];
            // lerp: acc + (1-wx)*v0 + wx*v1 == fma(wx, v1-v0, acc+v0)
            aL = fmaf(wxL[k], v1L - v0L, aL + v0L);
            aR = fmaf(wxR[k], v1R - v0R, aR + v0R);
        }
        f2v o;
        o.x = aL * (1.0f / 7.0f);
        o.y = aR * (1.0f / 7.0f);
        *(f2v*)(ob + (size_t)p * NPIX + idoff) = o;
        __syncthreads();   // line buffer reuse fence
    }
}

extern "C" void kernel_launch(void* const* d_in, const int* in_sizes, int n_in,
                              void* d_out, int out_size, void* d_ws, size_t ws_size,
                              hipStream_t stream) {
    const float* img  = (const float*)d_in[0];
    const float* zoom = (const float*)d_in[1];
    float* out = (float*)d_out;

    dim3 block(256);
    dim3 grid(IH * GROUPS);      // 2048 blocks = 8 per CU, single round
    zoomblur_kernel<<<grid, block, 0, stream>>>(img, zoom, out);
}

// Round 6
// 37.247 us; speedup vs baseline: 1.7549x; 1.7549x over previous
//
#include <hip/hip_runtime.h>

#define IW 512
#define IH 512
#define NPIX (IH * IW)
#define NPLANES 24      // B*C
#define NK 6            // steps 1..6 (step 0 is exact identity)
#define GROUPS 8        // plane-split: 3 planes per block; group == bid%8 == XCD
#define PPT (NPLANES / GROUPS)
#define LROW 520        // LDS line stride: 4 guard + 512 data + 4 guard
#define GOFF 4          // data starts at slot 4 (16B-aligned stage writes)

typedef float f4v __attribute__((ext_vector_type(4)));

struct RowTap { int rowA; float t0, t1; };

// Row taps for one step (block-uniform). Branch-free remap zeroes weights of
// out-of-range tap rows (vertical zero-pad).
__device__ inline RowTap row_prep(float inv, float yf) {
    const float ysv = fmaf(yf, inv, 256.0f);
    const float fy  = floorf(ysv);
    const float wy  = ysv - fy;
    const int y0 = (int)fy;
    const int yb = min(max(y0, 0), IH - 2);
    RowTap rt;
    rt.t0 = (yb == y0 ? 1.0f - wy : 0.0f) + (yb == y0 + 1 ? wy : 0.0f);
    rt.t1 = (yb + 1 == y0 ? 1.0f - wy : 0.0f) + (yb + 1 == y0 + 1 ? wy : 0.0f);
    rt.rowA = yb * IW;
    return rt;
}

__global__ __launch_bounds__(256, 8) void zoomblur_kernel(
    const float* __restrict__ img,
    const float* __restrict__ zoomf,
    float* __restrict__ out)
{
    __shared__ float rrow[NK * LROW];   // 12.5 KB: 6 guarded row-interp lines

    const int tid   = threadIdx.x;
    const int bid   = blockIdx.x;
    const int group = bid & (GROUPS - 1);   // == bid%8 == XCD (round-robin)
    const int y     = bid >> 3;             // one output row per block

    const float zf = 0.85f + 0.30f * zoomf[0];
    const float dz = zf - 1.0f;
    const float yf  = (float)y - 256.0f;
    // split-pixel ownership: this thread computes x = tid and x = tid+256
    // -> LDS read lane-stride ~= inv (<=2-way bank aliasing, free)
    const float xfA = (float)tid - 256.0f;
    const float xfB = (float)tid;

    // per-step inverse scales (rcp: ~1ulp, inside 2e-2 tolerance)
    float invs[NK];
#pragma unroll
    for (int s = 1; s <= NK; ++s)
        invs[s - 1] = __builtin_amdgcn_rcpf(fmaf((float)s * (1.0f / 6.0f), dz, 1.0f));

    // ---- per-thread column taps (guard-zero: clamp into zeroed guard slots,
    //      keep plain interior weights) ----
    int   offA[NK], offB[NK];
    float wxA[NK], wxB[NK];
#pragma unroll
    for (int k = 0; k < NK; ++k) {
        const float inv = invs[k];
        const float xsA = fmaf(xfA, inv, 256.0f);
        const float xsB = fmaf(xfB, inv, 256.0f);
        const float fxA = floorf(xsA);
        const float fxB = floorf(xsB);
        wxA[k] = xsA - fxA;
        wxB[k] = xsB - fxB;
        const int xA = min(max((int)fxA, -2), IW);   // slots 2..516
        const int xB = min(max((int)fxB, -2), IW);
        offA[k] = k * LROW + GOFF + xA;
        offB[k] = k * LROW + GOFF + xB;
    }

    // ---- staging role: thread stages col-quad cq of 3 of the 6 lines ----
    const int sbase = tid >> 7;             // 0 or 1
    const int cq    = (tid & 127) << 2;     // 0..508
    const RowTap r0 = row_prep(sbase ? invs[1] : invs[0], yf);
    const RowTap r1 = row_prep(sbase ? invs[3] : invs[2], yf);
    const RowTap r2 = row_prep(sbase ? invs[5] : invs[4], yf);
    float* wbase = &rrow[sbase * LROW + GOFF + cq];   // lines sbase, sbase+2, sbase+4

    // zero guard slots once (stage writes never touch them)
    if (tid < 48) {
        const int line = tid >> 3;
        const int j    = tid & 7;
        const int slot = (j < 4) ? j : 512 + j;   // 0..3, 516..519
        rrow[line * LROW + slot] = 0.0f;
    }

    const int idoff = y * IW + tid;
    const size_t pbase = (size_t)(group * PPT) * NPIX;
    const float* __restrict__ ib = img + pbase;
    float* __restrict__       ob = out + pbase;

#pragma unroll 1
    for (int p = 0; p < PPT; ++p) {
        const float* __restrict__ base = ib + (size_t)p * NPIX;
        // stage: 6 coalesced row loads -> 3 row-interpolated lines (L2-hot)
        const f4v a0 = *(const f4v*)(base + r0.rowA + cq);
        const f4v b0 = *(const f4v*)(base + r0.rowA + IW + cq);
        const f4v a1 = *(const f4v*)(base + r1.rowA + cq);
        const f4v b1 = *(const f4v*)(base + r1.rowA + IW + cq);
        const f4v a2 = *(const f4v*)(base + r2.rowA + cq);
        const f4v b2 = *(const f4v*)(base + r2.rowA + IW + cq);
        const float idA = base[idoff];          // step 0: exact identity
        const float idB = base[idoff + 256];
        *(f4v*)(wbase)            = r0.t0 * a0 + r0.t1 * b0;
        *(f4v*)(wbase + 2 * LROW) = r1.t0 * a1 + r1.t1 * b1;
        *(f4v*)(wbase + 4 * LROW) = r2.t0 * a2 + r2.t1 * b2;
        __syncthreads();

        float aA = idA, aB = idB;
#pragma unroll
        for (int k = 0; k < NK; ++k) {
            const float v0A = rrow[offA[k]];
            const float v1A = rrow[offA[k] + 1];
            const float v0B = rrow[offB[k]];
            const float v1B = rrow[offB[k] + 1];
            // lerp: acc + (1-wx)*v0 + wx*v1 == fma(wx, v1-v0, acc+v0)
            aA = fmaf(wxA[k], v1A - v0A, aA + v0A);
            aB = fmaf(wxB[k], v1B - v0B, aB + v0B);
        }
        float* op = ob + (size_t)p * NPIX + idoff;
        op[0]   = aA * (1.0f / 7.0f);
        op[256] = aB * (1.0f / 7.0f);
        __syncthreads();   // line-buffer reuse fence
    }
}

extern "C" void kernel_launch(void* const* d_in, const int* in_sizes, int n_in,
                              void* d_out, int out_size, void* d_ws, size_t ws_size,
                              hipStream_t stream) {
    const float* img  = (const float*)d_in[0];
    const float* zoom = (const float*)d_in[1];
    float* out = (float*)d_out;

    dim3 block(256);
    dim3 grid(IH * GROUPS);      // 4096 blocks; bid&7 == XCD -> 3 planes/XCD L2-resident
    zoomblur_kernel<<<grid, block, 0, stream>>>(img, zoom, out);
}

// Round 7
// 33.810 us; speedup vs baseline: 1.9333x; 1.1017x over previous
//
#include <hip/hip_runtime.h>

#define IW 512
#define IH 512
#define NPIX (IH * IW)
#define NK 6            // steps 1..6 (step 0 is exact identity)
#define GROUPS 8        // group == bid%8 == XCD -> 3 planes per XCD, L2-resident
#define PPT 3
#define LROW 520        // 4 guard + 512 data + 4 guard
#define GOFF 4

typedef float f4v __attribute__((ext_vector_type(4)));

struct RowTap { int rowA; float t0, t1; };

// Row taps for one step (block-uniform). Branch-free remap zeroes weights of
// out-of-range tap rows (vertical zero-pad).
__device__ inline RowTap row_prep(float inv, float yf) {
    const float ysv = fmaf(yf, inv, 256.0f);
    const float fy  = floorf(ysv);
    const float wy  = ysv - fy;
    const int y0 = (int)fy;
    const int yb = min(max(y0, 0), IH - 2);
    RowTap rt;
    rt.t0 = (yb == y0 ? 1.0f - wy : 0.0f) + (yb == y0 + 1 ? wy : 0.0f);
    rt.t1 = (yb + 1 == y0 ? 1.0f - wy : 0.0f) + (yb + 1 == y0 + 1 ? wy : 0.0f);
    rt.rowA = yb * IW;
    return rt;
}

__global__ __launch_bounds__(256, 6) void zoomblur_kernel(
    const float* __restrict__ img,
    const float* __restrict__ zoomf,
    float* __restrict__ out)
{
    __shared__ float rrow[NK * LROW];   // 12.5 KB: 6 guarded row-interp lines

    const int tid   = threadIdx.x;
    const int bid   = blockIdx.x;
    const int group = bid & (GROUPS - 1);   // == XCD (round-robin dispatch)
    const int y     = bid >> 3;             // one output row per block

    const float zf = 0.85f + 0.30f * zoomf[0];
    const float dz = zf - 1.0f;
    const float yf  = (float)y - 256.0f;
    // split-pixel ownership: x = tid and x = tid+256 -> LDS lane-stride ~ inv
    const float xfA = (float)tid - 256.0f;
    const float xfB = (float)tid;

    float invs[NK];
#pragma unroll
    for (int s = 1; s <= NK; ++s)
        invs[s - 1] = __builtin_amdgcn_rcpf(fmaf((float)s * (1.0f / 6.0f), dz, 1.0f));

    // per-thread column taps; guard-zero: clamp into zeroed guard slots,
    // keep plain interior weights
    int   offA[NK], offB[NK];
    float wxA[NK], wxB[NK];
#pragma unroll
    for (int k = 0; k < NK; ++k) {
        const float inv = invs[k];
        const float xsA = fmaf(xfA, inv, 256.0f);
        const float xsB = fmaf(xfB, inv, 256.0f);
        const float fxA = floorf(xsA);
        const float fxB = floorf(xsB);
        wxA[k] = xsA - fxA;
        wxB[k] = xsB - fxB;
        const int xA = min(max((int)fxA, -2), IW);   // slots 2..516
        const int xB = min(max((int)fxB, -2), IW);
        offA[k] = k * LROW + GOFF + xA;
        offB[k] = k * LROW + GOFF + xB;
    }

    // staging role: thread stages col-quad cq of lines {sbase, sbase+2, sbase+4}
    const int sbase = tid >> 7;             // 0 or 1
    const int cq    = (tid & 127) << 2;     // 0..508
    const RowTap r0 = row_prep(sbase ? invs[1] : invs[0], yf);
    const RowTap r1 = row_prep(sbase ? invs[3] : invs[2], yf);
    const RowTap r2 = row_prep(sbase ? invs[5] : invs[4], yf);
    float* wbase = &rrow[sbase * LROW + GOFF + cq];

    // zero guard slots once (stage writes never touch them)
    if (tid < 48) {
        const int line = tid >> 3;
        const int j    = tid & 7;
        const int slot = (j < 4) ? j : 512 + j;   // 0..3, 516..519
        rrow[line * LROW + slot] = 0.0f;
    }

    const int idoff = y * IW + tid;
    const size_t pbase = (size_t)(group * PPT) * NPIX;
    const float* __restrict__ ib = img + pbase;
    float* __restrict__       ob = out + pbase;

    // ---- prologue: load + row-lerp plane 0 into registers ----
    f4v L0, L1, L2;
    float idA, idB;
    {
        const float* __restrict__ base = ib;
        const f4v a0 = *(const f4v*)(base + r0.rowA + cq);
        const f4v b0 = *(const f4v*)(base + r0.rowA + IW + cq);
        const f4v a1 = *(const f4v*)(base + r1.rowA + cq);
        const f4v b1 = *(const f4v*)(base + r1.rowA + IW + cq);
        const f4v a2 = *(const f4v*)(base + r2.rowA + cq);
        const f4v b2 = *(const f4v*)(base + r2.rowA + IW + cq);
        idA = base[idoff];
        idB = base[idoff + 256];
        L0 = r0.t0 * a0 + r0.t1 * b0;
        L1 = r1.t0 * a1 + r1.t1 * b1;
        L2 = r2.t0 * a2 + r2.t1 * b2;
    }

#pragma unroll 1
    for (int p = 0; p < PPT; ++p) {
        // publish this plane's row-interp lines
        *(f4v*)(wbase)            = L0;
        *(f4v*)(wbase + 2 * LROW) = L1;
        *(f4v*)(wbase + 4 * LROW) = L2;
        const float cA = idA, cB = idB;   // capture before prefetch overwrite
        __syncthreads();

        // T14 issue-early: next plane's loads + row-lerp overlap the LDS compute
        if (p + 1 < PPT) {
            const float* __restrict__ np = ib + (size_t)(p + 1) * NPIX;
            const f4v a0 = *(const f4v*)(np + r0.rowA + cq);
            const f4v b0 = *(const f4v*)(np + r0.rowA + IW + cq);
            const f4v a1 = *(const f4v*)(np + r1.rowA + cq);
            const f4v b1 = *(const f4v*)(np + r1.rowA + IW + cq);
            const f4v a2 = *(const f4v*)(np + r2.rowA + cq);
            const f4v b2 = *(const f4v*)(np + r2.rowA + IW + cq);
            idA = np[idoff];
            idB = np[idoff + 256];
            L0 = r0.t0 * a0 + r0.t1 * b0;
            L1 = r1.t0 * a1 + r1.t1 * b1;
            L2 = r2.t0 * a2 + r2.t1 * b2;
        }

        float aA = cA, aB = cB;
#pragma unroll
        for (int k = 0; k < NK; ++k) {
            const float v0A = rrow[offA[k]];
            const float v1A = rrow[offA[k] + 1];
            const float v0B = rrow[offB[k]];
            const float v1B = rrow[offB[k] + 1];
            // lerp: acc + (1-wx)*v0 + wx*v1 == fma(wx, v1-v0, acc+v0)
            aA = fmaf(wxA[k], v1A - v0A, aA + v0A);
            aB = fmaf(wxB[k], v1B - v0B, aB + v0B);
        }
        float* op = ob + (size_t)p * NPIX + idoff;
        op[0]   = aA * (1.0f / 7.0f);
        op[256] = aB * (1.0f / 7.0f);
        __syncthreads();   // line-buffer reuse fence
    }
}

extern "C" void kernel_launch(void* const* d_in, const int* in_sizes, int n_in,
                              void* d_out, int out_size, void* d_ws, size_t ws_size,
                              hipStream_t stream) {
    const float* img  = (const float*)d_in[0];
    const float* zoom = (const float*)d_in[1];
    float* out = (float*)d_out;

    dim3 block(256);
    dim3 grid(IH * GROUPS);      // 4096 blocks; bid&7 == XCD
    zoomblur_kernel<<<grid, block, 0, stream>>>(img, zoom, out);
}

// Round 8
// 22.696 us; speedup vs baseline: 2.8800x; 1.4897x over previous
//
#include <hip/hip_runtime.h>

#define IW 512
#define IH 512
#define NPIX (IH * IW)
#define NK 6            // steps 1..6 (step 0 is exact identity)
#define LROW 520        // 4 guard + 512 data + 4 guard
#define GOFF 4

typedef float f4v __attribute__((ext_vector_type(4)));

struct RowTap { int rowA; float t0, t1; };

// Row taps for one step (block-uniform). Branch-free remap zeroes weights of
// out-of-range tap rows (vertical zero-pad).
__device__ inline RowTap row_prep(float inv, float yf) {
    const float ysv = fmaf(yf, inv, 256.0f);
    const float fy  = floorf(ysv);
    const float wy  = ysv - fy;
    const int y0 = (int)fy;
    const int yb = min(max(y0, 0), IH - 2);
    RowTap rt;
    rt.t0 = (yb == y0 ? 1.0f - wy : 0.0f) + (yb == y0 + 1 ? wy : 0.0f);
    rt.t1 = (yb + 1 == y0 ? 1.0f - wy : 0.0f) + (yb + 1 == y0 + 1 ? wy : 0.0f);
    rt.rowA = yb * IW;
    return rt;
}

__global__ __launch_bounds__(256, 8) void zoomblur_kernel(
    const float* __restrict__ img,
    const float* __restrict__ zoomf,
    float* __restrict__ out)
{
    __shared__ float rrow[NK * LROW];   // 12.5 KB: 6 guarded row-interp lines

    const int tid   = threadIdx.x;
    const int bid   = blockIdx.x;
    // plane = bid%24: plane%8 == bid%8 == XCD -> each XCD touches only its
    // 3 planes (3 MB, L2-resident). row = bid/24.
    const int plane = bid % 24;
    const int y     = bid / 24;

    const float zf = 0.85f + 0.30f * zoomf[0];
    const float dz = zf - 1.0f;
    const float yf  = (float)y - 256.0f;
    // split-pixel ownership: x = tid and x = tid+256 -> LDS lane-stride ~ inv
    const float xfA = (float)tid - 256.0f;
    const float xfB = (float)tid;

    float invs[NK];
#pragma unroll
    for (int s = 1; s <= NK; ++s)
        invs[s - 1] = __builtin_amdgcn_rcpf(fmaf((float)s * (1.0f / 6.0f), dz, 1.0f));

    // per-thread column taps; guard-zero: clamp into zeroed guard slots,
    // keep plain interior weights
    int   offA[NK], offB[NK];
    float wxA[NK], wxB[NK];
#pragma unroll
    for (int k = 0; k < NK; ++k) {
        const float inv = invs[k];
        const float xsA = fmaf(xfA, inv, 256.0f);
        const float xsB = fmaf(xfB, inv, 256.0f);
        const float fxA = floorf(xsA);
        const float fxB = floorf(xsB);
        wxA[k] = xsA - fxA;
        wxB[k] = xsB - fxB;
        const int xA = min(max((int)fxA, -2), IW);   // slots 2..516
        const int xB = min(max((int)fxB, -2), IW);
        offA[k] = k * LROW + GOFF + xA;
        offB[k] = k * LROW + GOFF + xB;
    }

    // staging role: thread stages col-quad cq of lines {sbase, sbase+2, sbase+4}
    const int sbase = tid >> 7;             // 0 or 1
    const int cq    = (tid & 127) << 2;     // 0..508
    const RowTap r0 = row_prep(sbase ? invs[1] : invs[0], yf);
    const RowTap r1 = row_prep(sbase ? invs[3] : invs[2], yf);
    const RowTap r2 = row_prep(sbase ? invs[5] : invs[4], yf);
    float* wbase = &rrow[sbase * LROW + GOFF + cq];

    // zero guard slots (stage writes never touch them)
    if (tid < 48) {
        const int line = tid >> 3;
        const int j    = tid & 7;
        const int slot = (j < 4) ? j : 512 + j;   // 0..3, 516..519
        rrow[line * LROW + slot] = 0.0f;
    }

    const float* __restrict__ base = img + (size_t)plane * NPIX;
    const int idoff = y * IW + tid;

    // stage: 6 coalesced b128 loads -> 3 row-interpolated lines
    const f4v a0 = *(const f4v*)(base + r0.rowA + cq);
    const f4v b0 = *(const f4v*)(base + r0.rowA + IW + cq);
    const f4v a1 = *(const f4v*)(base + r1.rowA + cq);
    const f4v b1 = *(const f4v*)(base + r1.rowA + IW + cq);
    const f4v a2 = *(const f4v*)(base + r2.rowA + cq);
    const f4v b2 = *(const f4v*)(base + r2.rowA + IW + cq);
    const float idA = base[idoff];          // step 0: exact identity
    const float idB = base[idoff + 256];
    *(f4v*)(wbase)            = r0.t0 * a0 + r0.t1 * b0;
    *(f4v*)(wbase + 2 * LROW) = r1.t0 * a1 + r1.t1 * b1;
    *(f4v*)(wbase + 4 * LROW) = r2.t0 * a2 + r2.t1 * b2;
    __syncthreads();    // the only barrier in the kernel

    float aA = idA, aB = idB;
#pragma unroll
    for (int k = 0; k < NK; ++k) {
        const float v0A = rrow[offA[k]];
        const float v1A = rrow[offA[k] + 1];
        const float v0B = rrow[offB[k]];
        const float v1B = rrow[offB[k] + 1];
        // lerp: acc + (1-wx)*v0 + wx*v1 == fma(wx, v1-v0, acc+v0)
        aA = fmaf(wxA[k], v1A - v0A, aA + v0A);
        aB = fmaf(wxB[k], v1B - v0B, aB + v0B);
    }
    // nontemporal: output is never re-read; don't pollute L2 dirty state
    float* op = out + (size_t)plane * NPIX + idoff;
    __builtin_nontemporal_store(aA * (1.0f / 7.0f), op);
    __builtin_nontemporal_store(aB * (1.0f / 7.0f), op + 256);
}

extern "C" void kernel_launch(void* const* d_in, const int* in_sizes, int n_in,
                              void* d_out, int out_size, void* d_ws, size_t ws_size,
                              hipStream_t stream) {
    const float* img  = (const float*)d_in[0];
    const float* zoom = (const float*)d_in[1];
    float* out = (float*)d_out;

    dim3 block(256);
    dim3 grid(IH * 24);      // 12288 independent (row, plane) blocks
    zoomblur_kernel<<<grid, block, 0, stream>>>(img, zoom, out);
}

// Round 9
// 19.279 us; speedup vs baseline: 3.3905x; 1.1773x over previous
//
#include <hip/hip_runtime.h>

#define IW 512
#define IH 512
#define NPIX (IH * IW)
#define NK 6            // steps 1..6 (step 0 is exact identity)
#define GROUPS 8        // group == bid&7 == XCD -> 3 planes per XCD, L2-resident
#define PPT 3
#define LROW 520        // 4 guard + 512 data + 4 guard
#define GOFF 4

typedef float f4v __attribute__((ext_vector_type(4)));

struct RowTap { int rowA; float t0, t1; };

// Row taps for one step (block-uniform). Branch-free remap zeroes weights of
// out-of-range tap rows (vertical zero-pad).
__device__ inline RowTap row_prep(float inv, float yf) {
    const float ysv = fmaf(yf, inv, 256.0f);
    const float fy  = floorf(ysv);
    const float wy  = ysv - fy;
    const int y0 = (int)fy;
    const int yb = min(max(y0, 0), IH - 2);
    RowTap rt;
    rt.t0 = (yb == y0 ? 1.0f - wy : 0.0f) + (yb == y0 + 1 ? wy : 0.0f);
    rt.t1 = (yb + 1 == y0 ? 1.0f - wy : 0.0f) + (yb + 1 == y0 + 1 ? wy : 0.0f);
    rt.rowA = yb * IW;
    return rt;
}

// issue 6 row loads + 2 identity loads for one plane into registers
#define STAGE_LOAD(base_) do {                                  \
    const float* __restrict__ _b = (base_);                     \
    a0 = *(const f4v*)(_b + r0.rowA + cq);                      \
    b0 = *(const f4v*)(_b + r0.rowA + IW + cq);                 \
    a1 = *(const f4v*)(_b + r1.rowA + cq);                      \
    b1 = *(const f4v*)(_b + r1.rowA + IW + cq);                 \
    a2 = *(const f4v*)(_b + r2.rowA + cq);                      \
    b2 = *(const f4v*)(_b + r2.rowA + IW + cq);                 \
    nIdA = _b[idoff];                                           \
    nIdB = _b[idoff + 256];                                     \
} while (0)

// row-lerp the staged registers and publish into LDS buffer B
#define STAGE_WRITE(B) do {                                     \
    *(f4v*)&rrow[B][woff]            = r0.t0 * a0 + r0.t1 * b0; \
    *(f4v*)&rrow[B][woff + 2 * LROW] = r1.t0 * a1 + r1.t1 * b1; \
    *(f4v*)&rrow[B][woff + 4 * LROW] = r2.t0 * a2 + r2.t1 * b2; \
} while (0)

// horizontal lerp for both owned pixels from LDS buffer B, NT store
#define COMPUTE_STORE(B, cA_, cB_, op_) do {                    \
    float aA = (cA_), aB = (cB_);                               \
    _Pragma("unroll")                                           \
    for (int k = 0; k < NK; ++k) {                              \
        const float v0A = rrow[B][offA[k]];                     \
        const float v1A = rrow[B][offA[k] + 1];                 \
        const float v0B = rrow[B][offB[k]];                     \
        const float v1B = rrow[B][offB[k] + 1];                 \
        aA = fmaf(wxA[k], v1A - v0A, aA + v0A);                 \
        aB = fmaf(wxB[k], v1B - v0B, aB + v0B);                 \
    }                                                           \
    float* _o = (op_);                                          \
    __builtin_nontemporal_store(aA * (1.0f / 7.0f), _o);        \
    __builtin_nontemporal_store(aB * (1.0f / 7.0f), _o + 256);  \
} while (0)

__global__ __launch_bounds__(256, 6) void zoomblur_kernel(
    const float* __restrict__ img,
    const float* __restrict__ zoomf,
    float* __restrict__ out)
{
    __shared__ float rrow[2][NK * LROW];   // 25 KB: double-buffered 6 lines

    const int tid   = threadIdx.x;
    const int bid   = blockIdx.x;
    const int group = bid & (GROUPS - 1);   // == XCD (round-robin dispatch)
    const int y     = bid >> 3;             // one output row per block

    const float zf = 0.85f + 0.30f * zoomf[0];
    const float dz = zf - 1.0f;
    const float yf  = (float)y - 256.0f;
    // split-pixel ownership: x = tid and x = tid+256
    const float xfA = (float)tid - 256.0f;
    const float xfB = (float)tid;

    float invs[NK];
#pragma unroll
    for (int s = 1; s <= NK; ++s)
        invs[s - 1] = __builtin_amdgcn_rcpf(fmaf((float)s * (1.0f / 6.0f), dz, 1.0f));

    // per-thread column taps; guard-zero: clamp into zeroed guard slots,
    // keep plain interior weights
    int   offA[NK], offB[NK];
    float wxA[NK], wxB[NK];
#pragma unroll
    for (int k = 0; k < NK; ++k) {
        const float inv = invs[k];
        const float xsA = fmaf(xfA, inv, 256.0f);
        const float xsB = fmaf(xfB, inv, 256.0f);
        const float fxA = floorf(xsA);
        const float fxB = floorf(xsB);
        wxA[k] = xsA - fxA;
        wxB[k] = xsB - fxB;
        const int xA = min(max((int)fxA, -2), IW);   // slots 2..516
        const int xB = min(max((int)fxB, -2), IW);
        offA[k] = k * LROW + GOFF + xA;
        offB[k] = k * LROW + GOFF + xB;
    }

    // staging role: thread stages col-quad cq of lines {sbase, sbase+2, sbase+4}
    const int sbase = tid >> 7;             // 0 or 1
    const int cq    = (tid & 127) << 2;     // 0..508
    const RowTap r0 = row_prep(sbase ? invs[1] : invs[0], yf);
    const RowTap r1 = row_prep(sbase ? invs[3] : invs[2], yf);
    const RowTap r2 = row_prep(sbase ? invs[5] : invs[4], yf);
    const int woff = sbase * LROW + GOFF + cq;

    // zero guard slots of both buffers once (stage writes never touch them)
    if (tid < 96) {
        const int line = tid >> 3;              // 0..11
        const int j    = tid & 7;
        const int slot = (j < 4) ? j : 512 + j; // 0..3, 516..519
        const int buf  = line >= NK;
        const int l    = buf ? line - NK : line;
        rrow[buf][l * LROW + slot] = 0.0f;
    }

    const int idoff = y * IW + tid;
    const size_t pbase = (size_t)(group * PPT) * NPIX;
    const float* __restrict__ ib = img + pbase;
    float* __restrict__       ob = out + pbase;

    f4v a0, b0, a1, b1, a2, b2;
    float nIdA, nIdB;

    // ---- software pipeline: stage p0 -> [compute p | prefetch p+1] ----
    STAGE_LOAD(ib);                       // plane 0
    float cIdA = nIdA, cIdB = nIdB;
    STAGE_WRITE(0);
    __syncthreads();                      // buf0 ready
    STAGE_LOAD(ib + NPIX);                // plane 1 loads fly over compute 0

    COMPUTE_STORE(0, cIdA, cIdB, ob + idoff);
    cIdA = nIdA; cIdB = nIdB;
    STAGE_WRITE(1);                       // consume plane-1 loads
    __syncthreads();                      // buf1 ready; buf0 reads done
    STAGE_LOAD(ib + 2 * NPIX);            // plane 2 loads fly over compute 1

    COMPUTE_STORE(1, cIdA, cIdB, ob + NPIX + idoff);
    cIdA = nIdA; cIdB = nIdB;
    STAGE_WRITE(0);                       // safe: buf0 reads finished pre-barrier
    __syncthreads();                      // buf0 ready again

    COMPUTE_STORE(0, cIdA, cIdB, ob + 2 * NPIX + idoff);
}

extern "C" void kernel_launch(void* const* d_in, const int* in_sizes, int n_in,
                              void* d_out, int out_size, void* d_ws, size_t ws_size,
                              hipStream_t stream) {
    const float* img  = (const float*)d_in[0];
    const float* zoom = (const float*)d_in[1];
    float* out = (float*)d_out;

    dim3 block(256);
    dim3 grid(IH * GROUPS);      // 4096 blocks; bid&7 == XCD, 3 planes each
    zoomblur_kernel<<<grid, block, 0, stream>>>(img, zoom, out);
}